// Round 15
// baseline (267.635 us; speedup 1.0000x reference)
//
#include <hip/hip_runtime.h>

#define BT 32768
#define TSEQ 128

constexpr float EPSF = 1.1920929e-07f;

typedef __attribute__((ext_vector_type(8))) short bf16x8;
typedef __attribute__((ext_vector_type(4))) float f32x4;

__device__ __forceinline__ float sigm(float z) { return 1.f / (1.f + __expf(-z)); }

__device__ __forceinline__ short bf16c(float f) {
  union { float f; unsigned u; } v; v.f = f;
  unsigned r = v.u + 0x7FFFu + ((v.u >> 16) & 1u);
  return (short)(r >> 16);
}
__device__ __forceinline__ float bf2f(short s) {
  union { unsigned u; float f; } v; v.u = ((unsigned)(unsigned short)s) << 16;
  return v.f;
}

__device__ __forceinline__ float red64(float v) {
  v += __shfl_xor(v, 1);  v += __shfl_xor(v, 2);  v += __shfl_xor(v, 4);
  v += __shfl_xor(v, 8);  v += __shfl_xor(v, 16); v += __shfl_xor(v, 32);
  return v;
}
__device__ __forceinline__ float red32(float v) {
  v += __shfl_xor(v, 1); v += __shfl_xor(v, 2); v += __shfl_xor(v, 4);
  v += __shfl_xor(v, 8); v += __shfl_xor(v, 16);
  return v;
}
__device__ __forceinline__ float red16(float v) {
  v += __shfl_xor(v, 1); v += __shfl_xor(v, 2); v += __shfl_xor(v, 4); v += __shfl_xor(v, 8);
  return v;
}
__device__ __forceinline__ float redmax16(float v) {
  v = fmaxf(v, __shfl_xor(v, 1)); v = fmaxf(v, __shfl_xor(v, 2));
  v = fmaxf(v, __shfl_xor(v, 4)); v = fmaxf(v, __shfl_xor(v, 8));
  return v;
}
__device__ __forceinline__ void load8(float* d, const float* p) {
  const float4 a = *reinterpret_cast<const float4*>(p);
  const float4 b = *reinterpret_cast<const float4*>(p + 4);
  d[0]=a.x; d[1]=a.y; d[2]=a.z; d[3]=a.w; d[4]=b.x; d[5]=b.y; d[6]=b.z; d[7]=b.w;
}

// ---------------------------------------------------------------------------
// prep: bf16 transposed weights [N][K] + packed mhc weights/biases + bf16 table.
// ---------------------------------------------------------------------------
__global__ __launch_bounds__(256) void prep(
    const float* __restrict__ qkv_w, const float* __restrict__ proj_w,
    const float* __restrict__ mlp_w1, const float* __restrict__ mlp_w2,
    const float* __restrict__ val_w, const float* __restrict__ key_w,
    const float* __restrict__ table,
    const float* __restrict__ a_res_w, const float* __restrict__ a_pre_w,
    const float* __restrict__ a_post_w,
    const float* __restrict__ m_res_w, const float* __restrict__ m_pre_w,
    const float* __restrict__ m_post_w,
    const float* __restrict__ a_res_b, const float* __restrict__ a_pre_b,
    const float* __restrict__ a_post_b,
    const float* __restrict__ m_res_b, const float* __restrict__ m_pre_b,
    const float* __restrict__ m_post_b,
    short* __restrict__ wt_qkv, short* __restrict__ wt_proj,
    short* __restrict__ wt_mlp1, short* __restrict__ wt_mlp2,
    short* __restrict__ wt_eng, short* __restrict__ wpk_a,
    short* __restrict__ wpk_m, float* __restrict__ bpk_a,
    float* __restrict__ bpk_m, unsigned short* __restrict__ tableb)
{
  const int idx = blockIdx.x * 256 + threadIdx.x;
  if (idx < 49152) {
    const int n = idx >> 7, k = idx & 127;
    wt_qkv[idx] = bf16c(qkv_w[k * 384 + n]);
  } else if (idx < 65536) {
    const int j = idx - 49152; const int n = j >> 7, k = j & 127;
    wt_proj[j] = bf16c(proj_w[k * 128 + n]);
  } else if (idx < 131072) {
    const int j = idx - 65536; const int n = j >> 7, k = j & 127;
    wt_mlp1[j] = bf16c(mlp_w1[k * 512 + n]);
  } else if (idx < 196608) {
    const int j = idx - 131072; const int n = j >> 9, k = j & 511;
    wt_mlp2[j] = bf16c(mlp_w2[k * 128 + n]);
  } else if (idx < 360448) {
    const int j = idx - 196608; const int n = j >> 8, k = j & 255;
    float v;
    if (n < 128) v = val_w[k * 128 + n];
    else v = key_w[(size_t)((n - 128) >> 7) * 32768 + k * 128 + (n & 127)];
    wt_eng[j] = bf16c(v);
  } else if (idx < 376832) {
    const int j = idx - 360448; const int r = j >> 9, k = j & 511;
    float v = 0.f;
    if (r < 16) v = a_res_w[k * 16 + r];
    else if (r < 20) v = a_pre_w[k * 4 + (r - 16)];
    else if (r < 24) v = a_post_w[k * 4 + (r - 20)];
    wpk_a[j] = bf16c(v);
  } else if (idx < 393216) {
    const int j = idx - 376832; const int r = j >> 9, k = j & 511;
    float v = 0.f;
    if (r < 16) v = m_res_w[k * 16 + r];
    else if (r < 20) v = m_pre_w[k * 4 + (r - 16)];
    else if (r < 24) v = m_post_w[k * 4 + (r - 20)];
    wpk_m[j] = bf16c(v);
  } else if (idx < 393280) {
    const int j = idx - 393216;
    if (j < 32) {
      float v = 0.f;
      if (j < 16) v = a_res_b[j];
      else if (j < 20) v = a_pre_b[j - 16];
      else if (j < 24) v = a_post_b[j - 20];
      bpk_a[j] = v;
    } else {
      const int r = j - 32;
      float v = 0.f;
      if (r < 16) v = m_res_b[r];
      else if (r < 20) v = m_pre_b[r - 16];
      else if (r < 24) v = m_post_b[r - 20];
      bpk_m[r] = v;
    }
  } else if (idx < 393280 + 1048576) {
    const int j = idx - 393280;
    tableb[j] = (unsigned short)bf16c(table[j]);
  }
}

// ---------------------------------------------------------------------------
// MFMA GEMM, N=32 (mhc projection). bf16 A [BT][512]. Tile 64x32, BK=64.
// Fused rmsnorm: A*rinv[row]*csc[k] during staging.
// ---------------------------------------------------------------------------
__global__ __launch_bounds__(256) void mgemm32(
    const unsigned short* __restrict__ Ab, const int lda,
    const short* __restrict__ WT, const float* __restrict__ bias,
    float* __restrict__ out, const int K,
    const float* __restrict__ rinv, const float* __restrict__ csc)
{
  __shared__ short As[64 * 64];
  __shared__ short Bs[32 * 64];
  const int tid = threadIdx.x;
  const int i0 = blockIdx.x * 64;
  const int w = tid >> 6, l = tid & 63;
  const int wm = w >> 1, wn = w & 1;
  const int kg = l >> 4, lr = l & 15;
  f32x4 acc[2];
  acc[0] = {0.f, 0.f, 0.f, 0.f};
  acc[1] = {0.f, 0.f, 0.f, 0.f};

  for (int kc = 0; kc < K; kc += 64) {
    __syncthreads();
#pragma unroll
    for (int p = 0; p < 2; ++p) {
      const int idx = p * 256 + tid;
      const int r = idx >> 3, ko = idx & 7;
      const bf16x8 v = *reinterpret_cast<const bf16x8*>(Ab + (size_t)(i0 + r) * lda + kc + ko * 8);
      const float rs = rinv[i0 + r];
      const float4 ca = *reinterpret_cast<const float4*>(csc + kc + ko * 8);
      const float4 cb = *reinterpret_cast<const float4*>(csc + kc + ko * 8 + 4);
      bf16x8 o;
      o[0] = bf16c(bf2f(v[0]) * rs * ca.x);
      o[1] = bf16c(bf2f(v[1]) * rs * ca.y);
      o[2] = bf16c(bf2f(v[2]) * rs * ca.z);
      o[3] = bf16c(bf2f(v[3]) * rs * ca.w);
      o[4] = bf16c(bf2f(v[4]) * rs * cb.x);
      o[5] = bf16c(bf2f(v[5]) * rs * cb.y);
      o[6] = bf16c(bf2f(v[6]) * rs * cb.z);
      o[7] = bf16c(bf2f(v[7]) * rs * cb.w);
      *reinterpret_cast<bf16x8*>(&As[r * 64 + ((ko ^ (r & 7)) << 3)]) = o;
    }
    {
      const int r = tid >> 3, slb = tid & 7;
      const bf16x8 v = *reinterpret_cast<const bf16x8*>(WT + (size_t)r * K + kc + slb * 8);
      *reinterpret_cast<bf16x8*>(&Bs[r * 64 + ((slb ^ (r & 7)) << 3)]) = v;
    }
    __syncthreads();
#pragma unroll
    for (int ks = 0; ks < 2; ++ks) {
      const int slot = ks * 4 + kg;
      bf16x8 af[2], bft;
#pragma unroll
      for (int mi = 0; mi < 2; ++mi) {
        const int r = wm * 32 + mi * 16 + lr;
        af[mi] = *reinterpret_cast<const bf16x8*>(&As[r * 64 + ((slot ^ (r & 7)) << 3)]);
      }
      {
        const int rb = wn * 16 + lr;
        bft = *reinterpret_cast<const bf16x8*>(&Bs[rb * 64 + ((slot ^ (rb & 7)) << 3)]);
      }
#pragma unroll
      for (int mi = 0; mi < 2; ++mi)
        acc[mi] = __builtin_amdgcn_mfma_f32_16x16x32_bf16(af[mi], bft, acc[mi], 0, 0, 0);
    }
  }
#pragma unroll
  for (int mi = 0; mi < 2; ++mi) {
    const int col = wn * 16 + lr;
    const float bv = bias[col];
#pragma unroll
    for (int j = 0; j < 4; ++j) {
      const int row = i0 + wm * 32 + mi * 16 + kg * 4 + j;
      out[(size_t)row * 32 + col] = acc[mi][j] + bv;
    }
  }
}

// ---------------------------------------------------------------------------
// engram MFMA GEMM: ngram-hash + bf16-table gather fused into A staging.
// by==0 -> vbaseb (bf16, +val_b); by 1..4 -> krawb (bf16).
// ---------------------------------------------------------------------------
__global__ __launch_bounds__(256) void eng_mgemm(
    const int* __restrict__ ids, const int* __restrict__ mults,
    const unsigned short* __restrict__ tableb, const float* __restrict__ val_b,
    const short* __restrict__ wt_eng,
    unsigned short* __restrict__ vbaseb, unsigned short* __restrict__ krawb)
{
  __shared__ int hid[128][4];
  __shared__ short As[128 * 64];
  __shared__ short Bs[128 * 64];
  const int tid = threadIdx.x;
  const int i0 = blockIdx.x * 128;
  const int by = blockIdx.y;
  const int c0 = by * 128;
#pragma unroll
  for (int p = 0; p < 2; ++p) {
    const int idx = tid + p * 256;
    const int r = idx >> 2, wh = idx & 3;
    const int i = i0 + r;
    const int b = i >> 7, tt = i & 127;
    const int* __restrict__ row = ids + b * TSEQ;
    const int g2 = row[tt];
    const int g1 = (tt >= 1) ? row[tt - 1] : 0;
    const int g0 = (tt >= 2) ? row[tt - 2] : 0;
    int h;
    if (wh == 0)      h = ((g1 * mults[0]) ^ (g2 * mults[1])) & 4095;
    else if (wh == 1) h = (((g1 * mults[3]) ^ (g2 * mults[4])) & 4095) + 4096;
    else if (wh == 2) h = (((g0 * mults[6]) ^ (g1 * mults[7]) ^ (g2 * mults[8])) & 4095) + 8192;
    else              h = (((g0 * mults[9]) ^ (g1 * mults[10]) ^ (g2 * mults[11])) & 4095) + 12288;
    hid[r][wh] = h;
  }
  const int w = tid >> 6, l = tid & 63;
  const int wr = (w >> 1) * 64, wc = (w & 1) * 64;
  f32x4 acc[4][4];
#pragma unroll
  for (int mi = 0; mi < 4; ++mi)
#pragma unroll
    for (int ni = 0; ni < 4; ++ni) acc[mi][ni] = {0.f, 0.f, 0.f, 0.f};

  const int bsl = tid & 7;

  for (int kc = 0; kc < 256; kc += 64) {
    const int seg = kc >> 6;
    __syncthreads();
#pragma unroll
    for (int p = 0; p < 4; ++p) {
      const int idx = p * 256 + tid;
      const int r = idx >> 3, ko = idx & 7;
      const bf16x8 v = *reinterpret_cast<const bf16x8*>(tableb + (size_t)hid[r][seg] * 64 + ko * 8);
      *reinterpret_cast<bf16x8*>(&As[r * 64 + ((ko ^ (r & 7)) << 3)]) = v;
    }
#pragma unroll
    for (int p = 0; p < 4; ++p) {
      const int r = (tid >> 3) + p * 32;
      const bf16x8 v = *reinterpret_cast<const bf16x8*>(wt_eng + (size_t)(c0 + r) * 256 + kc + bsl * 8);
      *reinterpret_cast<bf16x8*>(&Bs[r * 64 + ((bsl ^ (r & 7)) << 3)]) = v;
    }
    __syncthreads();
    const int kg = l >> 4, lr = l & 15;
#pragma unroll
    for (int ks = 0; ks < 2; ++ks) {
      const int slot = ks * 4 + kg;
      bf16x8 af[4], bft[4];
#pragma unroll
      for (int mi = 0; mi < 4; ++mi) {
        const int r = wr + mi * 16 + lr;
        af[mi] = *reinterpret_cast<const bf16x8*>(&As[r * 64 + ((slot ^ (r & 7)) << 3)]);
      }
#pragma unroll
      for (int ni = 0; ni < 4; ++ni) {
        const int r = wc + ni * 16 + lr;
        bft[ni] = *reinterpret_cast<const bf16x8*>(&Bs[r * 64 + ((slot ^ (r & 7)) << 3)]);
      }
#pragma unroll
      for (int mi = 0; mi < 4; ++mi)
#pragma unroll
        for (int ni = 0; ni < 4; ++ni)
          acc[mi][ni] = __builtin_amdgcn_mfma_f32_16x16x32_bf16(af[mi], bft[ni], acc[mi][ni], 0, 0, 0);
    }
  }
  const int lr = l & 15, hi = l >> 4;
#pragma unroll
  for (int mi = 0; mi < 4; ++mi)
#pragma unroll
    for (int ni = 0; ni < 4; ++ni) {
      const int col = wc + ni * 16 + lr;
#pragma unroll
      for (int j = 0; j < 4; ++j) {
        const int row = i0 + wr + mi * 16 + hi * 4 + j;
        if (by == 0)
          vbaseb[(size_t)row * 128 + col] = (unsigned short)bf16c(acc[mi][ni][j] + val_b[col]);
        else
          krawb[(size_t)row * 512 + (by - 1) * 128 + col] =
              (unsigned short)bf16c(acc[mi][ni][j]);
      }
    }
}

// ---------------------------------------------------------------------------
// fused engram gate + conv + residual. Block = 16 tokens, 512 thr / 8 waves.
// vbase bf16 in memory (f32 in LDS); x rows staged to LDS as bf16.
// ---------------------------------------------------------------------------
__global__ __launch_bounds__(512) void fused_gateconv(
    const unsigned short* __restrict__ krawb, const float* __restrict__ x,
    const unsigned short* __restrict__ vbaseb, const float* __restrict__ key_b,
    const float* __restrict__ nk_w, const float* __restrict__ nq_w,
    const float* __restrict__ conv_w, const float* __restrict__ cnw,
    unsigned short* __restrict__ xout, float* __restrict__ invout)
{
  __shared__ float vb[19 * 128];           // 9.5KB
  __shared__ unsigned short xs[16 * 512];  // 16KB (own-token x rows, bf16)
  __shared__ float gA[19][4];
  __shared__ float gG[19][4];
  const int tid = threadIdx.x;
  const size_t rowbase = (size_t)blockIdx.x * 16;
  const int tt0 = (int)(rowbase & 127);
  // stage vbase: 19 rows x 16 bf16x8 groups = 304
  if (tid < 304) {
    const int hs = tid >> 4, c8 = (tid & 15) * 8;
    float v[8] = {0.f, 0.f, 0.f, 0.f, 0.f, 0.f, 0.f, 0.f};
    if (tt0 - 3 + hs >= 0) {
      const bf16x8 b = *reinterpret_cast<const bf16x8*>(vbaseb + (rowbase - 3 + hs) * 128 + c8);
#pragma unroll
      for (int j = 0; j < 8; ++j) v[j] = bf2f(b[j]);
    }
#pragma unroll
    for (int j = 0; j < 8; ++j) vb[hs * 128 + c8 + j] = v[j];
  }
  __syncthreads();
  const int w = tid >> 6, l = tid & 63;
  // ---- gate phase: 19 tokens, wave per token, 8 waves; own-x rows -> LDS ----
  {
    const int s = l >> 4, li = l & 15, c0h = li * 8, j0 = l * 8;
    float kb[8], nk[8], nq[8];
    load8(kb, key_b + s * 128 + c0h);
    load8(nk, nk_w + s * 128 + c0h);
    load8(nq, nq_w + s * 128 + c0h);
    for (int it = 0; it < 3; ++it) {
      const int ht = it * 8 + w;
      if (ht >= 19) break;
      const int tt = tt0 - 3 + ht;
      if (tt < 0) {
        if (li == 0) { gG[ht][s] = 0.f; gA[ht][s] = 0.f; }
        continue;
      }
      const size_t rg = rowbase - 3 + ht;
      float kv[8], xv[8];
      {
        const bf16x8 kvb = *reinterpret_cast<const bf16x8*>(krawb + rg * 512 + j0);
#pragma unroll
        for (int jj = 0; jj < 8; ++jj) kv[jj] = bf2f(kvb[jj]);
      }
      load8(xv, x + rg * 512 + j0);
      if (ht >= 3) {
        bf16x8 xb;
#pragma unroll
        for (int jj = 0; jj < 8; ++jj) xb[jj] = bf16c(xv[jj]);
        *reinterpret_cast<bf16x8*>(&xs[(ht - 3) * 512 + j0]) = xb;
      }
      float ssk = 0.f, ssx = 0.f;
#pragma unroll
      for (int jj = 0; jj < 8; ++jj) {
        kv[jj] += kb[jj];
        ssk = fmaf(kv[jj], kv[jj], ssk);
        ssx = fmaf(xv[jj], xv[jj], ssx);
      }
      ssk = red16(ssk);
      ssx = red16(ssx);
      const float invk = rsqrtf(ssk * (1.f / 128.f) + EPSF);
      const float invq = rsqrtf(ssx * (1.f / 128.f) + EPSF);
      float dot = 0.f;
#pragma unroll
      for (int jj = 0; jj < 8; ++jj)
        dot = fmaf(kv[jj] * invk * nk[jj], xv[jj] * invq * nq[jj], dot);
      dot = red16(dot);
      const float gate = sigm(dot * 0.08838834764831843f); // 1/sqrt(128)
      const float2 vb2 = *reinterpret_cast<const float2*>(&vb[ht * 128 + l * 2]);
      float ssv = vb2.x * vb2.x + vb2.y * vb2.y;
      ssv = red64(ssv);
      const float A = gate * rsqrtf(gate * gate * (ssv * (1.f / 128.f)) + EPSF);
      if (li == 0) { gG[ht][s] = gate; gA[ht][s] = A; }
    }
  }
  __syncthreads();
  // ---- conv phase: 16 token-groups of 32 lanes, 1 token each ----
  {
    const int t = tid >> 5;           // local token 0..15; vb row = t+3
    const int c4l = tid & 31;
    const int cf = c4l * 4;
    const size_t rg = rowbase + t;
    float ssq = 0.f;
#pragma unroll
    for (int sj = 0; sj < 4; ++sj) {
      const int j = sj * 128 + cf;
      float4 cwe[4];
#pragma unroll
      for (int e = 0; e < 4; ++e)
        cwe[e] = *reinterpret_cast<const float4*>(conv_w + (size_t)(j + e) * 4);
      const float4 cn4 = *reinterpret_cast<const float4*>(cnw + j);
      float4 vbt[4]; float av[4];
#pragma unroll
      for (int kk = 0; kk < 4; ++kk) {
        vbt[kk] = *reinterpret_cast<const float4*>(&vb[(t + kk) * 128 + cf]);
        av[kk] = gA[t + kk][sj];
      }
      const float gg = gG[t + 3][sj];
      float4 accv;
      accv.x = vbt[0].x*av[0]*cwe[0].x + vbt[1].x*av[1]*cwe[0].y + vbt[2].x*av[2]*cwe[0].z + vbt[3].x*av[3]*cwe[0].w;
      accv.y = vbt[0].y*av[0]*cwe[1].x + vbt[1].y*av[1]*cwe[1].y + vbt[2].y*av[2]*cwe[1].z + vbt[3].y*av[3]*cwe[1].w;
      accv.z = vbt[0].z*av[0]*cwe[2].x + vbt[1].z*av[1]*cwe[2].y + vbt[2].z*av[2]*cwe[2].z + vbt[3].z*av[3]*cwe[2].w;
      accv.w = vbt[0].w*av[0]*cwe[3].x + vbt[1].w*av[1]*cwe[3].y + vbt[2].w*av[2]*cwe[3].z + vbt[3].w*av[3]*cwe[3].w;
      const ushort4 xb4 = *reinterpret_cast<const ushort4*>(&xs[t * 512 + j]);
      const float4 x4 = make_float4(bf2f((short)xb4.x), bf2f((short)xb4.y),
                                    bf2f((short)xb4.z), bf2f((short)xb4.w));
      const float y0 = accv.x * cn4.x, y1 = accv.y * cn4.y;
      const float y2 = accv.z * cn4.z, y3 = accv.w * cn4.w;
      float4 o;
      o.x = x4.x + vbt[3].x * gg + y0 * sigm(y0);
      o.y = x4.y + vbt[3].y * gg + y1 * sigm(y1);
      o.z = x4.z + vbt[3].z * gg + y2 * sigm(y2);
      o.w = x4.w + vbt[3].w * gg + y3 * sigm(y3);
      ushort4 ob;
      ob.x = (unsigned short)bf16c(o.x);
      ob.y = (unsigned short)bf16c(o.y);
      ob.z = (unsigned short)bf16c(o.z);
      ob.w = (unsigned short)bf16c(o.w);
      *reinterpret_cast<ushort4*>(xout + rg * 512 + j) = ob;
      ssq += o.x*o.x + o.y*o.y + o.z*o.z + o.w*o.w;
    }
    ssq = red32(ssq);
    if (c4l == 0) invout[rg] = rsqrtf(ssq * (1.f / 512.f) + EPSF);
  }
}

// ---------------------------------------------------------------------------
// mhc sink: bf16 state in, bf16 xa out.
// ---------------------------------------------------------------------------
__global__ __launch_bounds__(256) void mhc_sink2(
    const float* __restrict__ proj, const unsigned short* __restrict__ xin,
    const float* __restrict__ p_apre, const float* __restrict__ p_apost,
    const float* __restrict__ p_ares, const float* __restrict__ ln_w,
    unsigned short* __restrict__ xab, float* __restrict__ hres,
    float* __restrict__ hps)
{
  const int tid = threadIdx.x;
  const int l = tid & 63;
  const size_t i = (size_t)blockIdx.x * 4 + (tid >> 6);
  const float pv = proj[i * 32 + (l & 31)];
  const float apre = p_apre[0], apost = p_apost[0], ares = p_ares[0];
  const int n = l >> 4;
  const float hp = sigm(apre * __shfl(pv, 16 + n));
  float hsum = 0.f;
#pragma unroll
  for (int t2 = 0; t2 < 4; ++t2) hsum += 2.f * sigm(apost * __shfl(pv, 20 + t2));
  const float v = ares * pv;
  float rm = fmaxf(v, __shfl_xor(v, 1));
  rm = fmaxf(rm, __shfl_xor(rm, 2));
  float m = __expf(v - rm);
#pragma unroll
  for (int it = 0; it < 20; ++it) {
    float rs = m + __shfl_xor(m, 1);
    rs += __shfl_xor(rs, 2);
    m *= __builtin_amdgcn_rcpf(rs + 1e-6f);
    float cs = m + __shfl_xor(m, 4);
    cs += __shfl_xor(cs, 8);
    m *= __builtin_amdgcn_rcpf(cs + 1e-6f);
  }
  if (l < 16) hres[i * 16 + l] = m;
  if (l == 0) hps[i] = hsum;
  const int j0 = l * 8;
  float xv[8];
  {
    const bf16x8 xb = *reinterpret_cast<const bf16x8*>(xin + i * 512 + j0);
#pragma unroll
    for (int jj = 0; jj < 8; ++jj) xv[jj] = bf2f(xb[jj]);
  }
  float ag[8];
#pragma unroll
  for (int jj = 0; jj < 8; ++jj) {
    float a2 = hp * xv[jj];
    a2 += __shfl_xor(a2, 16);
    a2 += __shfl_xor(a2, 32);
    ag[jj] = a2;
  }
  float ssa = 0.f;
#pragma unroll
  for (int jj = 0; jj < 8; ++jj) ssa = fmaf(ag[jj], ag[jj], ssa);
  ssa = red16(ssa);
  const float inva = rsqrtf(ssa * (1.f / 128.f) + EPSF);
  if (l < 16) {
    float lnw[8];
    load8(lnw, ln_w + l * 8);
    bf16x8 o;
#pragma unroll
    for (int jj = 0; jj < 8; ++jj) o[jj] = bf16c(ag[jj] * inva * lnw[jj]);
    *reinterpret_cast<bf16x8*>(xab + i * 128 + l * 8) = o;
  }
}

// ---------------------------------------------------------------------------
// MFMA GEMM, bf16 A and bf16 OUTPUT.
// ---------------------------------------------------------------------------
template <int NT, int ACT>
__global__ __launch_bounds__(256) void mgemm_bf16A(
    const unsigned short* __restrict__ Ab, const short* __restrict__ WT,
    const float* __restrict__ bias, unsigned short* __restrict__ outp)
{
  __shared__ short As[128 * 64];
  __shared__ short Bs[128 * 64];
  const int tid = threadIdx.x;
  const int i0 = blockIdx.x * 128;
  const int c0 = blockIdx.y * 128;
  const int w = tid >> 6, l = tid & 63;
  const int wr = (w >> 1) * 64, wc = (w & 1) * 64;
  const int kg = l >> 4, lr = l & 15;
  f32x4 acc[4][4];
#pragma unroll
  for (int mi = 0; mi < 4; ++mi)
#pragma unroll
    for (int ni = 0; ni < 4; ++ni) acc[mi][ni] = {0.f, 0.f, 0.f, 0.f};

#pragma unroll
  for (int kc = 0; kc < 2; ++kc) {
    __syncthreads();
#pragma unroll
    for (int p = 0; p < 4; ++p) {
      const int idx = p * 256 + tid;
      const int r = idx >> 3, slb = idx & 7;
      const bf16x8 v = *reinterpret_cast<const bf16x8*>(Ab + (size_t)(i0 + r) * 128 + kc * 64 + slb * 8);
      *reinterpret_cast<bf16x8*>(&As[r * 64 + ((slb ^ (r & 7)) << 3)]) = v;
    }
#pragma unroll
    for (int p = 0; p < 4; ++p) {
      const int idx = p * 256 + tid;
      const int r = idx >> 3, slb = idx & 7;
      const bf16x8 v = *reinterpret_cast<const bf16x8*>(WT + (size_t)(c0 + r) * 128 + kc * 64 + slb * 8);
      *reinterpret_cast<bf16x8*>(&Bs[r * 64 + ((slb ^ (r & 7)) << 3)]) = v;
    }
    __syncthreads();
#pragma unroll
    for (int ks = 0; ks < 2; ++ks) {
      const int slot = ks * 4 + kg;
      bf16x8 af[4], bft[4];
#pragma unroll
      for (int mi = 0; mi < 4; ++mi) {
        const int r = wr + mi * 16 + lr;
        af[mi] = *reinterpret_cast<const bf16x8*>(&As[r * 64 + ((slot ^ (r & 7)) << 3)]);
      }
#pragma unroll
      for (int ni = 0; ni < 4; ++ni) {
        const int r = wc + ni * 16 + lr;
        bft[ni] = *reinterpret_cast<const bf16x8*>(&Bs[r * 64 + ((slot ^ (r & 7)) << 3)]);
      }
#pragma unroll
      for (int mi = 0; mi < 4; ++mi)
#pragma unroll
        for (int ni = 0; ni < 4; ++ni)
          acc[mi][ni] = __builtin_amdgcn_mfma_f32_16x16x32_bf16(af[mi], bft[ni], acc[mi][ni], 0, 0, 0);
    }
  }
#pragma unroll
  for (int mi = 0; mi < 4; ++mi)
#pragma unroll
    for (int ni = 0; ni < 4; ++ni) {
      const int col = c0 + wc + ni * 16 + lr;
      const float bv = bias[col];
#pragma unroll
      for (int j = 0; j < 4; ++j) {
        const int row = i0 + wr + mi * 16 + kg * 4 + j;
        float o = acc[mi][ni][j] + bv;
        if (ACT == 1) o = o * sigm(o);
        outp[(size_t)row * (NT * 128) + col] = (unsigned short)bf16c(o);
      }
    }
}

// ---------------------------------------------------------------------------
// fused GEMM (bf16 A, N=128) + mhc combine; hres/hps staged in LDS.
// ---------------------------------------------------------------------------
template <int KT, bool WITH_INV, bool OUTBF>
__global__ __launch_bounds__(512) void gemm_combine(
    const unsigned short* __restrict__ Ab, const int lda,
    const short* __restrict__ WT, const float* __restrict__ bias,
    const unsigned short* __restrict__ xst, const float* __restrict__ hres,
    const float* __restrict__ hps, void* __restrict__ outp,
    float* __restrict__ invout)
{
  __shared__ short As[64 * 64];
  __shared__ short Bs[128 * 64];
  __shared__ short yl[64 * 132];
  __shared__ float prt[64][2];
  __shared__ float hl[64 * 16];
  __shared__ float hpl[64];
  const int tid = threadIdx.x;
  const size_t i0 = (size_t)blockIdx.x * 64;
  const int w = tid >> 6, l = tid & 63;
  const int wm = w >> 2, wn = w & 3;
  const int kg = l >> 4, lr = l & 15;
  f32x4 acc[2][2];
#pragma unroll
  for (int mi = 0; mi < 2; ++mi)
#pragma unroll
    for (int ni = 0; ni < 2; ++ni) acc[mi][ni] = {0.f, 0.f, 0.f, 0.f};
#pragma unroll
  for (int kc = 0; kc < KT; ++kc) {
    __syncthreads();
    {
      const int r = tid >> 3, slb = tid & 7;
      const bf16x8 v = *reinterpret_cast<const bf16x8*>(Ab + (i0 + r) * lda + kc * 64 + slb * 8);
      *reinterpret_cast<bf16x8*>(&As[r * 64 + ((slb ^ (r & 7)) << 3)]) = v;
    }
#pragma unroll
    for (int p = 0; p < 2; ++p) {
      const int idx = p * 512 + tid;
      const int r = idx >> 3, slb = idx & 7;
      const bf16x8 v = *reinterpret_cast<const bf16x8*>(
          WT + (size_t)r * (KT * 64) + kc * 64 + slb * 8);
      *reinterpret_cast<bf16x8*>(&Bs[r * 64 + ((slb ^ (r & 7)) << 3)]) = v;
    }
    __syncthreads();
#pragma unroll
    for (int ks = 0; ks < 2; ++ks) {
      const int slot = ks * 4 + kg;
      bf16x8 af[2], bft[2];
#pragma unroll
      for (int mi = 0; mi < 2; ++mi) {
        const int r = wm * 32 + mi * 16 + lr;
        af[mi] = *reinterpret_cast<const bf16x8*>(&As[r * 64 + ((slot ^ (r & 7)) << 3)]);
      }
#pragma unroll
      for (int ni = 0; ni < 2; ++ni) {
        const int rb = wn * 32 + ni * 16 + lr;
        bft[ni] = *reinterpret_cast<const bf16x8*>(&Bs[rb * 64 + ((slot ^ (rb & 7)) << 3)]);
      }
#pragma unroll
      for (int mi = 0; mi < 2; ++mi)
#pragma unroll
        for (int ni = 0; ni < 2; ++ni)
          acc[mi][ni] = __builtin_amdgcn_mfma_f32_16x16x32_bf16(af[mi], bft[ni], acc[mi][ni], 0, 0, 0);
    }
  }
#pragma unroll
  for (int mi = 0; mi < 2; ++mi)
#pragma unroll
    for (int ni = 0; ni < 2; ++ni) {
      const int col = wn * 32 + ni * 16 + lr;
      const float bv = bias[col];
#pragma unroll
      for (int j = 0; j < 4; ++j) {
        const int row = wm * 32 + mi * 16 + kg * 4 + j;
        yl[row * 132 + col] = bf16c(acc[mi][ni][j] + bv);
      }
    }
  // stage hres/hps cooperatively
#pragma unroll
  for (int p = 0; p < 2; ++p) {
    const int idx = p * 512 + tid;
    hl[idx] = hres[(i0 + (idx >> 4)) * 16 + (idx & 15)];
  }
  if (tid < 64) hpl[tid] = hps[i0 + tid];
  __syncthreads();
  const int c = tid & 127, tl = tid >> 7;
  for (int k = 0; k < 16; ++k) {
    const int t = tl * 16 + k;
    const size_t rg = i0 + t;
    const float g = hpl[t];
    const float yv = bf2f(yl[t * 132 + c]) * g;
    float xm[4];
#pragma unroll
    for (int m = 0; m < 4; ++m) xm[m] = bf2f((short)xst[rg * 512 + m * 128 + c]);
    float ssq = 0.f;
#pragma unroll
    for (int n = 0; n < 4; ++n) {
      const float o = hl[t*16+n*4+0]*xm[0] + hl[t*16+n*4+1]*xm[1]
                    + hl[t*16+n*4+2]*xm[2] + hl[t*16+n*4+3]*xm[3] + yv;
      if (OUTBF)
        ((unsigned short*)outp)[rg * 512 + n * 128 + c] = (unsigned short)bf16c(o);
      else
        ((float*)outp)[rg * 512 + n * 128 + c] = o;
      if (WITH_INV) ssq = fmaf(o, o, ssq);
    }
    if (WITH_INV) {
      ssq = red64(ssq);
      if (l == 0) prt[t][(tid >> 6) & 1] = ssq;
    }
  }
  if (WITH_INV) {
    __syncthreads();
    if (tid < 64)
      invout[i0 + tid] = rsqrtf((prt[tid][0] + prt[tid][1]) * (1.f / 512.f) + EPSF);
  }
}

// ---------------------------------------------------------------------------
// MFMA causal attention; qkv input bf16 [BT][384], output y bf16 [BT][128].
// ---------------------------------------------------------------------------
__global__ __launch_bounds__(256) void attn_mfma(
    const unsigned short* __restrict__ qkv, unsigned short* __restrict__ y)
{
  __shared__ short Ks[128 * 32];
  __shared__ short Vt[32 * 128];
  __shared__ short Ps[4][32 * 128];
  const int tid = threadIdx.x;
  const int b = blockIdx.x >> 2, h = blockIdx.x & 3;
  const unsigned short* __restrict__ base = qkv + (size_t)b * 128 * 384 + h * 32;
#pragma unroll
  for (int p = 0; p < 2; ++p) {
    const int idx = tid + p * 256;
    const int s = idx >> 2, c8 = idx & 3;
    const bf16x8 v = *reinterpret_cast<const bf16x8*>(base + (size_t)s * 384 + 128 + c8 * 8);
    const int chunk = c8 ^ ((s >> 1) & 3);
    *reinterpret_cast<bf16x8*>(&Ks[s * 32 + chunk * 8]) = v;
  }
#pragma unroll
  for (int p = 0; p < 4; ++p) {
    const int idx = tid + p * 256;
    const int s = idx >> 3, c4 = idx & 7;
    const ushort4 v = *reinterpret_cast<const ushort4*>(base + (size_t)s * 384 + 256 + c4 * 4);
    const int schunk = s >> 3, soff = s & 7;
#pragma unroll
    for (int k = 0; k < 4; ++k) {
      const int d = c4 * 4 + k;
      const unsigned short vv = (k == 0) ? v.x : (k == 1) ? v.y : (k == 2) ? v.z : v.w;
      Vt[d * 128 + ((schunk ^ (d & 7)) << 3) + soff] = (short)vv;
    }
  }
  const int w = tid >> 6, l = tid & 63;
  const int g = l >> 4, lr = l & 15;
  bf16x8 qa[2];
#pragma unroll
  for (int mi = 0; mi < 2; ++mi) {
    const int row = w * 32 + mi * 16 + lr;
    qa[mi] = *reinterpret_cast<const bf16x8*>(base + (size_t)row * 384 + g * 8);
  }
  __syncthreads();
  const int ntmax = 2 * w + 1;
  bf16x8 ka[8];
#pragma unroll
  for (int nt = 0; nt < 8; ++nt)
    if (nt <= ntmax) {
      const int s = nt * 16 + lr;
      const int chunk = g ^ ((s >> 1) & 3);
      ka[nt] = *reinterpret_cast<const bf16x8*>(&Ks[s * 32 + chunk * 8]);
    }
  f32x4 sacc[2][8];
#pragma unroll
  for (int mi = 0; mi < 2; ++mi)
#pragma unroll
    for (int nt = 0; nt < 8; ++nt) sacc[mi][nt] = {0.f, 0.f, 0.f, 0.f};
#pragma unroll
  for (int mi = 0; mi < 2; ++mi)
#pragma unroll
    for (int nt = 0; nt < 8; ++nt)
      if (nt <= ntmax)
        sacc[mi][nt] = __builtin_amdgcn_mfma_f32_16x16x32_bf16(qa[mi], ka[nt], sacc[mi][nt], 0, 0, 0);
  const float scl = 0.17677669529663687f; // 1/sqrt(32)
  float rv[2][4];
  short* const pw = Ps[w];
#pragma unroll
  for (int mi = 0; mi < 2; ++mi) {
#pragma unroll
    for (int j = 0; j < 4; ++j) {
      const int row = w * 32 + mi * 16 + g * 4 + j;
      float mx = -3.4e38f;
#pragma unroll
      for (int nt = 0; nt < 8; ++nt)
        if (nt <= ntmax) {
          const int col = nt * 16 + lr;
          const float val = sacc[mi][nt][j] * scl;
          if (col <= row) mx = fmaxf(mx, val);
        }
      mx = redmax16(mx);
      float sum = 0.f;
      const int rl = mi * 16 + g * 4 + j;
#pragma unroll
      for (int nt = 0; nt < 8; ++nt)
        if (nt <= ntmax) {
          const int col = nt * 16 + lr;
          const float val = sacc[mi][nt][j] * scl;
          const float pv = (col <= row) ? __expf(val - mx) : 0.f;
          sum += pv;
          const int chunk = (2 * nt + (lr >> 3)) ^ (rl & 7);
          pw[rl * 128 + chunk * 8 + (lr & 7)] = bf16c(pv);
        }
      sum = red16(sum);
      rv[mi][j] = 1.f / sum;
    }
  }
  f32x4 oacc[2][2];
#pragma unroll
  for (int mi = 0; mi < 2; ++mi)
#pragma unroll
    for (int nt = 0; nt < 2; ++nt) oacc[mi][nt] = {0.f, 0.f, 0.f, 0.f};
#pragma unroll
  for (int kt = 0; kt < 4; ++kt)
    if (kt <= w) {
      bf16x8 pa[2], va[2];
#pragma unroll
      for (int mi = 0; mi < 2; ++mi) {
        const int rl = mi * 16 + lr;
        const int chunk = (4 * kt + g) ^ (rl & 7);
        pa[mi] = *reinterpret_cast<const bf16x8*>(&pw[rl * 128 + chunk * 8]);
      }
#pragma unroll
      for (int nt = 0; nt < 2; ++nt) {
        const int d = nt * 16 + lr;
        const int chunk = (4 * kt + g) ^ (d & 7);
        va[nt] = *reinterpret_cast<const bf16x8*>(&Vt[d * 128 + chunk * 8]);
      }
#pragma unroll
      for (int mi = 0; mi < 2; ++mi)
#pragma unroll
        for (int nt = 0; nt < 2; ++nt)
          oacc[mi][nt] = __builtin_amdgcn_mfma_f32_16x16x32_bf16(pa[mi], va[nt], oacc[mi][nt], 0, 0, 0);
    }
#pragma unroll
  for (int mi = 0; mi < 2; ++mi)
#pragma unroll
    for (int nt = 0; nt < 2; ++nt)
#pragma unroll
      for (int j = 0; j < 4; ++j) {
        const int row = w * 32 + mi * 16 + g * 4 + j;
        y[((size_t)b * 128 + row) * 128 + h * 32 + nt * 16 + lr] =
            (unsigned short)bf16c(oacc[mi][nt][j] * rv[mi][j]);
      }
}

// ---------------------------------------------------------------------------
extern "C" void kernel_launch(void* const* d_in, const int* in_sizes, int n_in,
                              void* d_out, int out_size, void* d_ws, size_t ws_size,
                              hipStream_t stream)
{
  const float* x        = (const float*)d_in[0];
  const int*   ids      = (const int*)d_in[1];
  const int*   mults    = (const int*)d_in[2];
  const float* table    = (const float*)d_in[3];
  const float* val_w    = (const float*)d_in[4];
  const float* val_b    = (const float*)d_in[5];
  const float* key_w    = (const float*)d_in[6];
  const float* key_b    = (const float*)d_in[7];
  const float* nq_w     = (const float*)d_in[8];
  const float* nk_w     = (const float*)d_in[9];
  const float* conv_w   = (const float*)d_in[10];
  const float* cnw      = (const float*)d_in[11];
  const float* a_coef   = (const float*)d_in[12];
  const float* a_pre_w  = (const float*)d_in[13];
  const float* a_pre_b  = (const float*)d_in[14];
  const float* a_post_w = (const float*)d_in[15];
  const float* a_post_b = (const float*)d_in[16];
  const float* a_res_w  = (const float*)d_in[17];
  const float* a_res_b  = (const float*)d_in[18];
  const float* a_apre   = (const float*)d_in[19];
  const float* a_apost  = (const float*)d_in[20];
  const float* a_ares   = (const float*)d_in[21];
  const float* a_ln_w   = (const float*)d_in[22];
  const float* qkv_w    = (const float*)d_in[23];
  const float* qkv_b    = (const float*)d_in[24];
  const float* proj_w   = (const float*)d_in[25];
  const float* proj_b   = (const float*)d_in[26];
  const float* m_coef   = (const float*)d_in[27];
  const float* m_pre_w  = (const float*)d_in[28];
  const float* m_pre_b  = (const float*)d_in[29];
  const float* m_post_w = (const float*)d_in[30];
  const float* m_post_b = (const float*)d_in[31];
  const float* m_res_w  = (const float*)d_in[32];
  const float* m_res_b  = (const float*)d_in[33];
  const float* m_apre   = (const float*)d_in[34];
  const float* m_apost  = (const float*)d_in[35];
  const float* m_ares   = (const float*)d_in[36];
  const float* m_ln_w   = (const float*)d_in[37];
  const float* mlp_w1   = (const float*)d_in[38];
  const float* mlp_b1   = (const float*)d_in[39];
  const float* mlp_w2   = (const float*)d_in[40];
  const float* mlp_b2   = (const float*)d_in[41];

  float* out = (float*)d_out;
  float* ws  = (float*)d_ws;
  float* vbase  = ws;                         // BT*128 slot (bf16 used)
  float* proj24 = vbase + (size_t)BT * 128;   // BT*32
  float* hresb  = proj24 + (size_t)BT * 32;   // BT*16
  float* hpsb   = hresb + (size_t)BT * 16;    // BT
  float* inv1   = hpsb + (size_t)BT;          // BT
  float* inv2   = inv1 + (size_t)BT;          // BT
  float* bpk_a  = inv2 + (size_t)BT;          // 32
  float* bpk_m  = bpk_a + 32;                 // 32
  short* wt_qkv  = (short*)(bpk_m + 32);      // 384*128
  short* wt_proj = wt_qkv  + 49152;           // 128*128
  short* wt_mlp1 = wt_proj + 16384;           // 512*128
  short* wt_mlp2 = wt_mlp1 + 65536;           // 128*512
  short* wt_eng  = wt_mlp2 + 65536;           // 640*256
  short* wpk_a   = wt_eng  + 163840;          // 32*512
  short* wpk_m   = wpk_a   + 16384;           // 32*512
  unsigned short* xab = (unsigned short*)(wpk_m + 16384); // BT*128 bf16 (attn-out alias)
  unsigned short* big = xab + (size_t)BT * 128;           // BT*512 bf16: kraw -> qkv -> h
  unsigned short* x1b = big + (size_t)BT * 512;           // BT*512 bf16 state x1
  unsigned short* x2b = x1b + (size_t)BT * 512;           // BT*512 bf16 state x2
  unsigned short* tableb = x2b + (size_t)BT * 512;        // 16384*64 bf16
  unsigned short* vbaseb = (unsigned short*)vbase;        // BT*128 bf16
  unsigned short* y1b = xab;                              // alias: attn out

  prep<<<5633, 256, 0, stream>>>(qkv_w, proj_w, mlp_w1, mlp_w2, val_w, key_w, table,
                                 a_res_w, a_pre_w, a_post_w, m_res_w, m_pre_w, m_post_w,
                                 a_res_b, a_pre_b, a_post_b, m_res_b, m_pre_b, m_post_b,
                                 wt_qkv, wt_proj, wt_mlp1, wt_mlp2, wt_eng,
                                 wpk_a, wpk_m, bpk_a, bpk_m, tableb);

  // ---- engram ----
  eng_mgemm<<<dim3(BT / 128, 5), 256, 0, stream>>>(ids, mults, tableb, val_b, wt_eng,
                                                   vbaseb, big);
  fused_gateconv<<<BT / 16, 512, 0, stream>>>(big, x, vbaseb, key_b, nk_w, nq_w,
                                              conv_w, cnw, x1b, inv1);

  // ---- mhc (attention) ----
  mgemm32<<<BT / 64, 256, 0, stream>>>(x1b, 512, wpk_a, bpk_a, proj24, 512, inv1, a_coef);
  mhc_sink2<<<BT / 4, 256, 0, stream>>>(proj24, x1b, a_apre, a_apost, a_ares, a_ln_w,
                                        xab, hresb, hpsb);
  mgemm_bf16A<3, 0><<<dim3(BT / 128, 3), 256, 0, stream>>>(xab, wt_qkv, qkv_b, big);
  attn_mfma<<<1024, 256, 0, stream>>>(big, y1b);
  gemm_combine<2, true, true><<<BT / 64, 512, 0, stream>>>(
      y1b, 128, wt_proj, proj_b, x1b, hresb, hpsb, (void*)x2b, inv2);

  // ---- mhc (mlp) ----
  mgemm32<<<BT / 64, 256, 0, stream>>>(x2b, 512, wpk_m, bpk_m, proj24, 512, inv2, m_coef);
  mhc_sink2<<<BT / 4, 256, 0, stream>>>(proj24, x2b, m_apre, m_apost, m_ares, m_ln_w,
                                        xab, hresb, hpsb);
  mgemm_bf16A<4, 1><<<dim3(BT / 128, 4), 256, 0, stream>>>(xab, wt_mlp1, mlp_b1, big);
  gemm_combine<8, false, false><<<BT / 64, 512, 0, stream>>>(
      big, 512, wt_mlp2, mlp_b2, x2b, hresb, hpsb, (void*)out, nullptr);

  (void)in_sizes; (void)n_in; (void)out_size; (void)ws_size;
}

// Round 16
// 265.316 us; speedup vs baseline: 1.0087x; 1.0087x over previous
//
#include <hip/hip_runtime.h>

#define BT 32768
#define TSEQ 128

constexpr float EPSF = 1.1920929e-07f;

typedef __attribute__((ext_vector_type(8))) short bf16x8;
typedef __attribute__((ext_vector_type(4))) float f32x4;

__device__ __forceinline__ float sigm(float z) { return 1.f / (1.f + __expf(-z)); }

__device__ __forceinline__ short bf16c(float f) {
  union { float f; unsigned u; } v; v.f = f;
  unsigned r = v.u + 0x7FFFu + ((v.u >> 16) & 1u);
  return (short)(r >> 16);
}
__device__ __forceinline__ float bf2f(short s) {
  union { unsigned u; float f; } v; v.u = ((unsigned)(unsigned short)s) << 16;
  return v.f;
}

__device__ __forceinline__ float red64(float v) {
  v += __shfl_xor(v, 1);  v += __shfl_xor(v, 2);  v += __shfl_xor(v, 4);
  v += __shfl_xor(v, 8);  v += __shfl_xor(v, 16); v += __shfl_xor(v, 32);
  return v;
}
__device__ __forceinline__ float red32(float v) {
  v += __shfl_xor(v, 1); v += __shfl_xor(v, 2); v += __shfl_xor(v, 4);
  v += __shfl_xor(v, 8); v += __shfl_xor(v, 16);
  return v;
}
__device__ __forceinline__ float red16(float v) {
  v += __shfl_xor(v, 1); v += __shfl_xor(v, 2); v += __shfl_xor(v, 4); v += __shfl_xor(v, 8);
  return v;
}
__device__ __forceinline__ float redmax16(float v) {
  v = fmaxf(v, __shfl_xor(v, 1)); v = fmaxf(v, __shfl_xor(v, 2));
  v = fmaxf(v, __shfl_xor(v, 4)); v = fmaxf(v, __shfl_xor(v, 8));
  return v;
}
__device__ __forceinline__ void load8(float* d, const float* p) {
  const float4 a = *reinterpret_cast<const float4*>(p);
  const float4 b = *reinterpret_cast<const float4*>(p + 4);
  d[0]=a.x; d[1]=a.y; d[2]=a.z; d[3]=a.w; d[4]=b.x; d[5]=b.y; d[6]=b.z; d[7]=b.w;
}

// ---------------------------------------------------------------------------
// prep: bf16 transposed weights [N][K] + packed mhc weights/biases + bf16 table.
// ---------------------------------------------------------------------------
__global__ __launch_bounds__(256) void prep(
    const float* __restrict__ qkv_w, const float* __restrict__ proj_w,
    const float* __restrict__ mlp_w1, const float* __restrict__ mlp_w2,
    const float* __restrict__ val_w, const float* __restrict__ key_w,
    const float* __restrict__ table,
    const float* __restrict__ a_res_w, const float* __restrict__ a_pre_w,
    const float* __restrict__ a_post_w,
    const float* __restrict__ m_res_w, const float* __restrict__ m_pre_w,
    const float* __restrict__ m_post_w,
    const float* __restrict__ a_res_b, const float* __restrict__ a_pre_b,
    const float* __restrict__ a_post_b,
    const float* __restrict__ m_res_b, const float* __restrict__ m_pre_b,
    const float* __restrict__ m_post_b,
    short* __restrict__ wt_qkv, short* __restrict__ wt_proj,
    short* __restrict__ wt_mlp1, short* __restrict__ wt_mlp2,
    short* __restrict__ wt_eng, short* __restrict__ wpk_a,
    short* __restrict__ wpk_m, float* __restrict__ bpk_a,
    float* __restrict__ bpk_m, unsigned short* __restrict__ tableb)
{
  const int idx = blockIdx.x * 256 + threadIdx.x;
  if (idx < 49152) {
    const int n = idx >> 7, k = idx & 127;
    wt_qkv[idx] = bf16c(qkv_w[k * 384 + n]);
  } else if (idx < 65536) {
    const int j = idx - 49152; const int n = j >> 7, k = j & 127;
    wt_proj[j] = bf16c(proj_w[k * 128 + n]);
  } else if (idx < 131072) {
    const int j = idx - 65536; const int n = j >> 7, k = j & 127;
    wt_mlp1[j] = bf16c(mlp_w1[k * 512 + n]);
  } else if (idx < 196608) {
    const int j = idx - 131072; const int n = j >> 9, k = j & 511;
    wt_mlp2[j] = bf16c(mlp_w2[k * 128 + n]);
  } else if (idx < 360448) {
    const int j = idx - 196608; const int n = j >> 8, k = j & 255;
    float v;
    if (n < 128) v = val_w[k * 128 + n];
    else v = key_w[(size_t)((n - 128) >> 7) * 32768 + k * 128 + (n & 127)];
    wt_eng[j] = bf16c(v);
  } else if (idx < 376832) {
    const int j = idx - 360448; const int r = j >> 9, k = j & 511;
    float v = 0.f;
    if (r < 16) v = a_res_w[k * 16 + r];
    else if (r < 20) v = a_pre_w[k * 4 + (r - 16)];
    else if (r < 24) v = a_post_w[k * 4 + (r - 20)];
    wpk_a[j] = bf16c(v);
  } else if (idx < 393216) {
    const int j = idx - 376832; const int r = j >> 9, k = j & 511;
    float v = 0.f;
    if (r < 16) v = m_res_w[k * 16 + r];
    else if (r < 20) v = m_pre_w[k * 4 + (r - 16)];
    else if (r < 24) v = m_post_w[k * 4 + (r - 20)];
    wpk_m[j] = bf16c(v);
  } else if (idx < 393280) {
    const int j = idx - 393216;
    if (j < 32) {
      float v = 0.f;
      if (j < 16) v = a_res_b[j];
      else if (j < 20) v = a_pre_b[j - 16];
      else if (j < 24) v = a_post_b[j - 20];
      bpk_a[j] = v;
    } else {
      const int r = j - 32;
      float v = 0.f;
      if (r < 16) v = m_res_b[r];
      else if (r < 20) v = m_pre_b[r - 16];
      else if (r < 24) v = m_post_b[r - 20];
      bpk_m[r] = v;
    }
  } else if (idx < 393280 + 1048576) {
    const int j = idx - 393280;
    tableb[j] = (unsigned short)bf16c(table[j]);
  }
}

// ---------------------------------------------------------------------------
// MFMA GEMM, N=32 (mhc projection). bf16 A [BT][512]. Tile 64x32, BK=64.
// Fused rmsnorm: A*rinv[row]*csc[k] during staging.
// ---------------------------------------------------------------------------
__global__ __launch_bounds__(256) void mgemm32(
    const unsigned short* __restrict__ Ab, const int lda,
    const short* __restrict__ WT, const float* __restrict__ bias,
    float* __restrict__ out, const int K,
    const float* __restrict__ rinv, const float* __restrict__ csc)
{
  __shared__ short As[64 * 64];
  __shared__ short Bs[32 * 64];
  const int tid = threadIdx.x;
  const int i0 = blockIdx.x * 64;
  const int w = tid >> 6, l = tid & 63;
  const int wm = w >> 1, wn = w & 1;
  const int kg = l >> 4, lr = l & 15;
  f32x4 acc[2];
  acc[0] = {0.f, 0.f, 0.f, 0.f};
  acc[1] = {0.f, 0.f, 0.f, 0.f};

  for (int kc = 0; kc < K; kc += 64) {
    __syncthreads();
#pragma unroll
    for (int p = 0; p < 2; ++p) {
      const int idx = p * 256 + tid;
      const int r = idx >> 3, ko = idx & 7;
      const bf16x8 v = *reinterpret_cast<const bf16x8*>(Ab + (size_t)(i0 + r) * lda + kc + ko * 8);
      const float rs = rinv[i0 + r];
      const float4 ca = *reinterpret_cast<const float4*>(csc + kc + ko * 8);
      const float4 cb = *reinterpret_cast<const float4*>(csc + kc + ko * 8 + 4);
      bf16x8 o;
      o[0] = bf16c(bf2f(v[0]) * rs * ca.x);
      o[1] = bf16c(bf2f(v[1]) * rs * ca.y);
      o[2] = bf16c(bf2f(v[2]) * rs * ca.z);
      o[3] = bf16c(bf2f(v[3]) * rs * ca.w);
      o[4] = bf16c(bf2f(v[4]) * rs * cb.x);
      o[5] = bf16c(bf2f(v[5]) * rs * cb.y);
      o[6] = bf16c(bf2f(v[6]) * rs * cb.z);
      o[7] = bf16c(bf2f(v[7]) * rs * cb.w);
      *reinterpret_cast<bf16x8*>(&As[r * 64 + ((ko ^ (r & 7)) << 3)]) = o;
    }
    {
      const int r = tid >> 3, slb = tid & 7;
      const bf16x8 v = *reinterpret_cast<const bf16x8*>(WT + (size_t)r * K + kc + slb * 8);
      *reinterpret_cast<bf16x8*>(&Bs[r * 64 + ((slb ^ (r & 7)) << 3)]) = v;
    }
    __syncthreads();
#pragma unroll
    for (int ks = 0; ks < 2; ++ks) {
      const int slot = ks * 4 + kg;
      bf16x8 af[2], bft;
#pragma unroll
      for (int mi = 0; mi < 2; ++mi) {
        const int r = wm * 32 + mi * 16 + lr;
        af[mi] = *reinterpret_cast<const bf16x8*>(&As[r * 64 + ((slot ^ (r & 7)) << 3)]);
      }
      {
        const int rb = wn * 16 + lr;
        bft = *reinterpret_cast<const bf16x8*>(&Bs[rb * 64 + ((slot ^ (rb & 7)) << 3)]);
      }
#pragma unroll
      for (int mi = 0; mi < 2; ++mi)
        acc[mi] = __builtin_amdgcn_mfma_f32_16x16x32_bf16(af[mi], bft, acc[mi], 0, 0, 0);
    }
  }
#pragma unroll
  for (int mi = 0; mi < 2; ++mi) {
    const int col = wn * 16 + lr;
    const float bv = bias[col];
#pragma unroll
    for (int j = 0; j < 4; ++j) {
      const int row = i0 + wm * 32 + mi * 16 + kg * 4 + j;
      out[(size_t)row * 32 + col] = acc[mi][j] + bv;
    }
  }
}

// ---------------------------------------------------------------------------
// engram MFMA GEMM: ngram-hash + bf16-table gather fused into A staging.
// by==0 -> vbaseb (bf16, +val_b); by 1..4 -> krawb (bf16).
// ---------------------------------------------------------------------------
__global__ __launch_bounds__(256) void eng_mgemm(
    const int* __restrict__ ids, const int* __restrict__ mults,
    const unsigned short* __restrict__ tableb, const float* __restrict__ val_b,
    const short* __restrict__ wt_eng,
    unsigned short* __restrict__ vbaseb, unsigned short* __restrict__ krawb)
{
  __shared__ int hid[128][4];
  __shared__ short As[128 * 64];
  __shared__ short Bs[128 * 64];
  const int tid = threadIdx.x;
  const int i0 = blockIdx.x * 128;
  const int by = blockIdx.y;
  const int c0 = by * 128;
#pragma unroll
  for (int p = 0; p < 2; ++p) {
    const int idx = tid + p * 256;
    const int r = idx >> 2, wh = idx & 3;
    const int i = i0 + r;
    const int b = i >> 7, tt = i & 127;
    const int* __restrict__ row = ids + b * TSEQ;
    const int g2 = row[tt];
    const int g1 = (tt >= 1) ? row[tt - 1] : 0;
    const int g0 = (tt >= 2) ? row[tt - 2] : 0;
    int h;
    if (wh == 0)      h = ((g1 * mults[0]) ^ (g2 * mults[1])) & 4095;
    else if (wh == 1) h = (((g1 * mults[3]) ^ (g2 * mults[4])) & 4095) + 4096;
    else if (wh == 2) h = (((g0 * mults[6]) ^ (g1 * mults[7]) ^ (g2 * mults[8])) & 4095) + 8192;
    else              h = (((g0 * mults[9]) ^ (g1 * mults[10]) ^ (g2 * mults[11])) & 4095) + 12288;
    hid[r][wh] = h;
  }
  const int w = tid >> 6, l = tid & 63;
  const int wr = (w >> 1) * 64, wc = (w & 1) * 64;
  f32x4 acc[4][4];
#pragma unroll
  for (int mi = 0; mi < 4; ++mi)
#pragma unroll
    for (int ni = 0; ni < 4; ++ni) acc[mi][ni] = {0.f, 0.f, 0.f, 0.f};

  const int bsl = tid & 7;

  for (int kc = 0; kc < 256; kc += 64) {
    const int seg = kc >> 6;
    __syncthreads();
#pragma unroll
    for (int p = 0; p < 4; ++p) {
      const int idx = p * 256 + tid;
      const int r = idx >> 3, ko = idx & 7;
      const bf16x8 v = *reinterpret_cast<const bf16x8*>(tableb + (size_t)hid[r][seg] * 64 + ko * 8);
      *reinterpret_cast<bf16x8*>(&As[r * 64 + ((ko ^ (r & 7)) << 3)]) = v;
    }
#pragma unroll
    for (int p = 0; p < 4; ++p) {
      const int r = (tid >> 3) + p * 32;
      const bf16x8 v = *reinterpret_cast<const bf16x8*>(wt_eng + (size_t)(c0 + r) * 256 + kc + bsl * 8);
      *reinterpret_cast<bf16x8*>(&Bs[r * 64 + ((bsl ^ (r & 7)) << 3)]) = v;
    }
    __syncthreads();
    const int kg = l >> 4, lr = l & 15;
#pragma unroll
    for (int ks = 0; ks < 2; ++ks) {
      const int slot = ks * 4 + kg;
      bf16x8 af[4], bft[4];
#pragma unroll
      for (int mi = 0; mi < 4; ++mi) {
        const int r = wr + mi * 16 + lr;
        af[mi] = *reinterpret_cast<const bf16x8*>(&As[r * 64 + ((slot ^ (r & 7)) << 3)]);
      }
#pragma unroll
      for (int ni = 0; ni < 4; ++ni) {
        const int r = wc + ni * 16 + lr;
        bft[ni] = *reinterpret_cast<const bf16x8*>(&Bs[r * 64 + ((slot ^ (r & 7)) << 3)]);
      }
#pragma unroll
      for (int mi = 0; mi < 4; ++mi)
#pragma unroll
        for (int ni = 0; ni < 4; ++ni)
          acc[mi][ni] = __builtin_amdgcn_mfma_f32_16x16x32_bf16(af[mi], bft[ni], acc[mi][ni], 0, 0, 0);
    }
  }
  const int lr = l & 15, hi = l >> 4;
#pragma unroll
  for (int mi = 0; mi < 4; ++mi)
#pragma unroll
    for (int ni = 0; ni < 4; ++ni) {
      const int col = wc + ni * 16 + lr;
#pragma unroll
      for (int j = 0; j < 4; ++j) {
        const int row = i0 + wr + mi * 16 + hi * 4 + j;
        if (by == 0)
          vbaseb[(size_t)row * 128 + col] = (unsigned short)bf16c(acc[mi][ni][j] + val_b[col]);
        else
          krawb[(size_t)row * 512 + (by - 1) * 128 + col] =
              (unsigned short)bf16c(acc[mi][ni][j]);
      }
    }
}

// ---------------------------------------------------------------------------
// fused engram gate + conv + residual. Block = 16 tokens, 512 thr / 8 waves.
// vbase bf16 in memory (f32 in LDS); x rows staged to LDS (f32).
// ---------------------------------------------------------------------------
__global__ __launch_bounds__(512) void fused_gateconv(
    const unsigned short* __restrict__ krawb, const float* __restrict__ x,
    const unsigned short* __restrict__ vbaseb, const float* __restrict__ key_b,
    const float* __restrict__ nk_w, const float* __restrict__ nq_w,
    const float* __restrict__ conv_w, const float* __restrict__ cnw,
    unsigned short* __restrict__ xout, float* __restrict__ invout)
{
  __shared__ float vb[19 * 128];   // 9.5KB
  __shared__ float xs[16 * 512];   // 32KB (own-token x rows)
  __shared__ float gA[19][4];
  __shared__ float gG[19][4];
  const int tid = threadIdx.x;
  const size_t rowbase = (size_t)blockIdx.x * 16;
  const int tt0 = (int)(rowbase & 127);
  // stage vbase: 19 rows x 16 bf16x8 groups = 304
  if (tid < 304) {
    const int hs = tid >> 4, c8 = (tid & 15) * 8;
    float v[8] = {0.f, 0.f, 0.f, 0.f, 0.f, 0.f, 0.f, 0.f};
    if (tt0 - 3 + hs >= 0) {
      const bf16x8 b = *reinterpret_cast<const bf16x8*>(vbaseb + (rowbase - 3 + hs) * 128 + c8);
#pragma unroll
      for (int j = 0; j < 8; ++j) v[j] = bf2f(b[j]);
    }
#pragma unroll
    for (int j = 0; j < 8; ++j) vb[hs * 128 + c8 + j] = v[j];
  }
  __syncthreads();
  const int w = tid >> 6, l = tid & 63;
  // ---- gate phase: 19 tokens, wave per token, 8 waves; own-x rows -> LDS ----
  {
    const int s = l >> 4, li = l & 15, c0h = li * 8, j0 = l * 8;
    float kb[8], nk[8], nq[8];
    load8(kb, key_b + s * 128 + c0h);
    load8(nk, nk_w + s * 128 + c0h);
    load8(nq, nq_w + s * 128 + c0h);
    for (int it = 0; it < 3; ++it) {
      const int ht = it * 8 + w;
      if (ht >= 19) break;
      const int tt = tt0 - 3 + ht;
      if (tt < 0) {
        if (li == 0) { gG[ht][s] = 0.f; gA[ht][s] = 0.f; }
        continue;
      }
      const size_t rg = rowbase - 3 + ht;
      float kv[8], xv[8];
      {
        const bf16x8 kvb = *reinterpret_cast<const bf16x8*>(krawb + rg * 512 + j0);
#pragma unroll
        for (int jj = 0; jj < 8; ++jj) kv[jj] = bf2f(kvb[jj]);
      }
      load8(xv, x + rg * 512 + j0);
      if (ht >= 3) {
        *reinterpret_cast<float4*>(&xs[(ht - 3) * 512 + j0]) =
            make_float4(xv[0], xv[1], xv[2], xv[3]);
        *reinterpret_cast<float4*>(&xs[(ht - 3) * 512 + j0 + 4]) =
            make_float4(xv[4], xv[5], xv[6], xv[7]);
      }
      float ssk = 0.f, ssx = 0.f;
#pragma unroll
      for (int jj = 0; jj < 8; ++jj) {
        kv[jj] += kb[jj];
        ssk = fmaf(kv[jj], kv[jj], ssk);
        ssx = fmaf(xv[jj], xv[jj], ssx);
      }
      ssk = red16(ssk);
      ssx = red16(ssx);
      const float invk = rsqrtf(ssk * (1.f / 128.f) + EPSF);
      const float invq = rsqrtf(ssx * (1.f / 128.f) + EPSF);
      float dot = 0.f;
#pragma unroll
      for (int jj = 0; jj < 8; ++jj)
        dot = fmaf(kv[jj] * invk * nk[jj], xv[jj] * invq * nq[jj], dot);
      dot = red16(dot);
      const float gate = sigm(dot * 0.08838834764831843f); // 1/sqrt(128)
      const float2 vb2 = *reinterpret_cast<const float2*>(&vb[ht * 128 + l * 2]);
      float ssv = vb2.x * vb2.x + vb2.y * vb2.y;
      ssv = red64(ssv);
      const float A = gate * rsqrtf(gate * gate * (ssv * (1.f / 128.f)) + EPSF);
      if (li == 0) { gG[ht][s] = gate; gA[ht][s] = A; }
    }
  }
  __syncthreads();
  // ---- conv phase: 16 token-groups of 32 lanes, 1 token each ----
  {
    const int t = tid >> 5;           // local token 0..15; vb row = t+3
    const int c4l = tid & 31;
    const int cf = c4l * 4;
    const size_t rg = rowbase + t;
    float ssq = 0.f;
#pragma unroll
    for (int sj = 0; sj < 4; ++sj) {
      const int j = sj * 128 + cf;
      float4 cwe[4];
#pragma unroll
      for (int e = 0; e < 4; ++e)
        cwe[e] = *reinterpret_cast<const float4*>(conv_w + (size_t)(j + e) * 4);
      const float4 cn4 = *reinterpret_cast<const float4*>(cnw + j);
      float4 vbt[4]; float av[4];
#pragma unroll
      for (int kk = 0; kk < 4; ++kk) {
        vbt[kk] = *reinterpret_cast<const float4*>(&vb[(t + kk) * 128 + cf]);
        av[kk] = gA[t + kk][sj];
      }
      const float gg = gG[t + 3][sj];
      float4 accv;
      accv.x = vbt[0].x*av[0]*cwe[0].x + vbt[1].x*av[1]*cwe[0].y + vbt[2].x*av[2]*cwe[0].z + vbt[3].x*av[3]*cwe[0].w;
      accv.y = vbt[0].y*av[0]*cwe[1].x + vbt[1].y*av[1]*cwe[1].y + vbt[2].y*av[2]*cwe[1].z + vbt[3].y*av[3]*cwe[1].w;
      accv.z = vbt[0].z*av[0]*cwe[2].x + vbt[1].z*av[1]*cwe[2].y + vbt[2].z*av[2]*cwe[2].z + vbt[3].z*av[3]*cwe[2].w;
      accv.w = vbt[0].w*av[0]*cwe[3].x + vbt[1].w*av[1]*cwe[3].y + vbt[2].w*av[2]*cwe[3].z + vbt[3].w*av[3]*cwe[3].w;
      const float4 x4 = *reinterpret_cast<const float4*>(&xs[t * 512 + j]);
      const float y0 = accv.x * cn4.x, y1 = accv.y * cn4.y;
      const float y2 = accv.z * cn4.z, y3 = accv.w * cn4.w;
      float4 o;
      o.x = x4.x + vbt[3].x * gg + y0 * sigm(y0);
      o.y = x4.y + vbt[3].y * gg + y1 * sigm(y1);
      o.z = x4.z + vbt[3].z * gg + y2 * sigm(y2);
      o.w = x4.w + vbt[3].w * gg + y3 * sigm(y3);
      ushort4 ob;
      ob.x = (unsigned short)bf16c(o.x);
      ob.y = (unsigned short)bf16c(o.y);
      ob.z = (unsigned short)bf16c(o.z);
      ob.w = (unsigned short)bf16c(o.w);
      *reinterpret_cast<ushort4*>(xout + rg * 512 + j) = ob;
      ssq += o.x*o.x + o.y*o.y + o.z*o.z + o.w*o.w;
    }
    ssq = red32(ssq);
    if (c4l == 0) invout[rg] = rsqrtf(ssq * (1.f / 512.f) + EPSF);
  }
}

// ---------------------------------------------------------------------------
// mhc sink: bf16 state in, bf16 xa out.
// ---------------------------------------------------------------------------
__global__ __launch_bounds__(256) void mhc_sink2(
    const float* __restrict__ proj, const unsigned short* __restrict__ xin,
    const float* __restrict__ p_apre, const float* __restrict__ p_apost,
    const float* __restrict__ p_ares, const float* __restrict__ ln_w,
    unsigned short* __restrict__ xab, float* __restrict__ hres,
    float* __restrict__ hps)
{
  const int tid = threadIdx.x;
  const int l = tid & 63;
  const size_t i = (size_t)blockIdx.x * 4 + (tid >> 6);
  const float pv = proj[i * 32 + (l & 31)];
  const float apre = p_apre[0], apost = p_apost[0], ares = p_ares[0];
  const int n = l >> 4;
  const float hp = sigm(apre * __shfl(pv, 16 + n));
  float hsum = 0.f;
#pragma unroll
  for (int t2 = 0; t2 < 4; ++t2) hsum += 2.f * sigm(apost * __shfl(pv, 20 + t2));
  const float v = ares * pv;
  float rm = fmaxf(v, __shfl_xor(v, 1));
  rm = fmaxf(rm, __shfl_xor(rm, 2));
  float m = __expf(v - rm);
#pragma unroll
  for (int it = 0; it < 20; ++it) {
    float rs = m + __shfl_xor(m, 1);
    rs += __shfl_xor(rs, 2);
    m *= __builtin_amdgcn_rcpf(rs + 1e-6f);
    float cs = m + __shfl_xor(m, 4);
    cs += __shfl_xor(cs, 8);
    m *= __builtin_amdgcn_rcpf(cs + 1e-6f);
  }
  if (l < 16) hres[i * 16 + l] = m;
  if (l == 0) hps[i] = hsum;
  const int j0 = l * 8;
  float xv[8];
  {
    const bf16x8 xb = *reinterpret_cast<const bf16x8*>(xin + i * 512 + j0);
#pragma unroll
    for (int jj = 0; jj < 8; ++jj) xv[jj] = bf2f(xb[jj]);
  }
  float ag[8];
#pragma unroll
  for (int jj = 0; jj < 8; ++jj) {
    float a2 = hp * xv[jj];
    a2 += __shfl_xor(a2, 16);
    a2 += __shfl_xor(a2, 32);
    ag[jj] = a2;
  }
  float ssa = 0.f;
#pragma unroll
  for (int jj = 0; jj < 8; ++jj) ssa = fmaf(ag[jj], ag[jj], ssa);
  ssa = red16(ssa);
  const float inva = rsqrtf(ssa * (1.f / 128.f) + EPSF);
  if (l < 16) {
    float lnw[8];
    load8(lnw, ln_w + l * 8);
    bf16x8 o;
#pragma unroll
    for (int jj = 0; jj < 8; ++jj) o[jj] = bf16c(ag[jj] * inva * lnw[jj]);
    *reinterpret_cast<bf16x8*>(xab + i * 128 + l * 8) = o;
  }
}

// ---------------------------------------------------------------------------
// MFMA GEMM, bf16 A and bf16 OUTPUT.
// ---------------------------------------------------------------------------
template <int NT, int ACT>
__global__ __launch_bounds__(256) void mgemm_bf16A(
    const unsigned short* __restrict__ Ab, const short* __restrict__ WT,
    const float* __restrict__ bias, unsigned short* __restrict__ outp)
{
  __shared__ short As[128 * 64];
  __shared__ short Bs[128 * 64];
  const int tid = threadIdx.x;
  const int i0 = blockIdx.x * 128;
  const int c0 = blockIdx.y * 128;
  const int w = tid >> 6, l = tid & 63;
  const int wr = (w >> 1) * 64, wc = (w & 1) * 64;
  const int kg = l >> 4, lr = l & 15;
  f32x4 acc[4][4];
#pragma unroll
  for (int mi = 0; mi < 4; ++mi)
#pragma unroll
    for (int ni = 0; ni < 4; ++ni) acc[mi][ni] = {0.f, 0.f, 0.f, 0.f};

#pragma unroll
  for (int kc = 0; kc < 2; ++kc) {
    __syncthreads();
#pragma unroll
    for (int p = 0; p < 4; ++p) {
      const int idx = p * 256 + tid;
      const int r = idx >> 3, slb = idx & 7;
      const bf16x8 v = *reinterpret_cast<const bf16x8*>(Ab + (size_t)(i0 + r) * 128 + kc * 64 + slb * 8);
      *reinterpret_cast<bf16x8*>(&As[r * 64 + ((slb ^ (r & 7)) << 3)]) = v;
    }
#pragma unroll
    for (int p = 0; p < 4; ++p) {
      const int idx = p * 256 + tid;
      const int r = idx >> 3, slb = idx & 7;
      const bf16x8 v = *reinterpret_cast<const bf16x8*>(WT + (size_t)(c0 + r) * 128 + kc * 64 + slb * 8);
      *reinterpret_cast<bf16x8*>(&Bs[r * 64 + ((slb ^ (r & 7)) << 3)]) = v;
    }
    __syncthreads();
#pragma unroll
    for (int ks = 0; ks < 2; ++ks) {
      const int slot = ks * 4 + kg;
      bf16x8 af[4], bft[4];
#pragma unroll
      for (int mi = 0; mi < 4; ++mi) {
        const int r = wr + mi * 16 + lr;
        af[mi] = *reinterpret_cast<const bf16x8*>(&As[r * 64 + ((slot ^ (r & 7)) << 3)]);
      }
#pragma unroll
      for (int ni = 0; ni < 4; ++ni) {
        const int r = wc + ni * 16 + lr;
        bft[ni] = *reinterpret_cast<const bf16x8*>(&Bs[r * 64 + ((slot ^ (r & 7)) << 3)]);
      }
#pragma unroll
      for (int mi = 0; mi < 4; ++mi)
#pragma unroll
        for (int ni = 0; ni < 4; ++ni)
          acc[mi][ni] = __builtin_amdgcn_mfma_f32_16x16x32_bf16(af[mi], bft[ni], acc[mi][ni], 0, 0, 0);
    }
  }
#pragma unroll
  for (int mi = 0; mi < 4; ++mi)
#pragma unroll
    for (int ni = 0; ni < 4; ++ni) {
      const int col = c0 + wc + ni * 16 + lr;
      const float bv = bias[col];
#pragma unroll
      for (int j = 0; j < 4; ++j) {
        const int row = i0 + wr + mi * 16 + kg * 4 + j;
        float o = acc[mi][ni][j] + bv;
        if (ACT == 1) o = o * sigm(o);
        outp[(size_t)row * (NT * 128) + col] = (unsigned short)bf16c(o);
      }
    }
}

// ---------------------------------------------------------------------------
// fused GEMM (bf16 A, N=128) + mhc combine; hres/hps staged in LDS.
// ---------------------------------------------------------------------------
template <int KT, bool WITH_INV, bool OUTBF>
__global__ __launch_bounds__(512) void gemm_combine(
    const unsigned short* __restrict__ Ab, const int lda,
    const short* __restrict__ WT, const float* __restrict__ bias,
    const unsigned short* __restrict__ xst, const float* __restrict__ hres,
    const float* __restrict__ hps, void* __restrict__ outp,
    float* __restrict__ invout)
{
  __shared__ short As[64 * 64];
  __shared__ short Bs[128 * 64];
  __shared__ short yl[64 * 132];
  __shared__ float prt[64][2];
  __shared__ float hl[64 * 16];
  __shared__ float hpl[64];
  const int tid = threadIdx.x;
  const size_t i0 = (size_t)blockIdx.x * 64;
  const int w = tid >> 6, l = tid & 63;
  const int wm = w >> 2, wn = w & 3;
  const int kg = l >> 4, lr = l & 15;
  f32x4 acc[2][2];
#pragma unroll
  for (int mi = 0; mi < 2; ++mi)
#pragma unroll
    for (int ni = 0; ni < 2; ++ni) acc[mi][ni] = {0.f, 0.f, 0.f, 0.f};
#pragma unroll
  for (int kc = 0; kc < KT; ++kc) {
    __syncthreads();
    {
      const int r = tid >> 3, slb = tid & 7;
      const bf16x8 v = *reinterpret_cast<const bf16x8*>(Ab + (i0 + r) * lda + kc * 64 + slb * 8);
      *reinterpret_cast<bf16x8*>(&As[r * 64 + ((slb ^ (r & 7)) << 3)]) = v;
    }
#pragma unroll
    for (int p = 0; p < 2; ++p) {
      const int idx = p * 512 + tid;
      const int r = idx >> 3, slb = idx & 7;
      const bf16x8 v = *reinterpret_cast<const bf16x8*>(
          WT + (size_t)r * (KT * 64) + kc * 64 + slb * 8);
      *reinterpret_cast<bf16x8*>(&Bs[r * 64 + ((slb ^ (r & 7)) << 3)]) = v;
    }
    __syncthreads();
#pragma unroll
    for (int ks = 0; ks < 2; ++ks) {
      const int slot = ks * 4 + kg;
      bf16x8 af[2], bft[2];
#pragma unroll
      for (int mi = 0; mi < 2; ++mi) {
        const int r = wm * 32 + mi * 16 + lr;
        af[mi] = *reinterpret_cast<const bf16x8*>(&As[r * 64 + ((slot ^ (r & 7)) << 3)]);
      }
#pragma unroll
      for (int ni = 0; ni < 2; ++ni) {
        const int rb = wn * 32 + ni * 16 + lr;
        bft[ni] = *reinterpret_cast<const bf16x8*>(&Bs[rb * 64 + ((slot ^ (rb & 7)) << 3)]);
      }
#pragma unroll
      for (int mi = 0; mi < 2; ++mi)
#pragma unroll
        for (int ni = 0; ni < 2; ++ni)
          acc[mi][ni] = __builtin_amdgcn_mfma_f32_16x16x32_bf16(af[mi], bft[ni], acc[mi][ni], 0, 0, 0);
    }
  }
#pragma unroll
  for (int mi = 0; mi < 2; ++mi)
#pragma unroll
    for (int ni = 0; ni < 2; ++ni) {
      const int col = wn * 32 + ni * 16 + lr;
      const float bv = bias[col];
#pragma unroll
      for (int j = 0; j < 4; ++j) {
        const int row = wm * 32 + mi * 16 + kg * 4 + j;
        yl[row * 132 + col] = bf16c(acc[mi][ni][j] + bv);
      }
    }
  // stage hres/hps cooperatively
#pragma unroll
  for (int p = 0; p < 2; ++p) {
    const int idx = p * 512 + tid;
    hl[idx] = hres[(i0 + (idx >> 4)) * 16 + (idx & 15)];
  }
  if (tid < 64) hpl[tid] = hps[i0 + tid];
  __syncthreads();
  const int c = tid & 127, tl = tid >> 7;
  for (int k = 0; k < 16; ++k) {
    const int t = tl * 16 + k;
    const size_t rg = i0 + t;
    const float g = hpl[t];
    const float yv = bf2f(yl[t * 132 + c]) * g;
    float xm[4];
#pragma unroll
    for (int m = 0; m < 4; ++m) xm[m] = bf2f((short)xst[rg * 512 + m * 128 + c]);
    float ssq = 0.f;
#pragma unroll
    for (int n = 0; n < 4; ++n) {
      const float o = hl[t*16+n*4+0]*xm[0] + hl[t*16+n*4+1]*xm[1]
                    + hl[t*16+n*4+2]*xm[2] + hl[t*16+n*4+3]*xm[3] + yv;
      if (OUTBF)
        ((unsigned short*)outp)[rg * 512 + n * 128 + c] = (unsigned short)bf16c(o);
      else
        ((float*)outp)[rg * 512 + n * 128 + c] = o;
      if (WITH_INV) ssq = fmaf(o, o, ssq);
    }
    if (WITH_INV) {
      ssq = red64(ssq);
      if (l == 0) prt[t][(tid >> 6) & 1] = ssq;
    }
  }
  if (WITH_INV) {
    __syncthreads();
    if (tid < 64)
      invout[i0 + tid] = rsqrtf((prt[tid][0] + prt[tid][1]) * (1.f / 512.f) + EPSF);
  }
}

// ---------------------------------------------------------------------------
// MFMA causal attention; qkv input bf16 [BT][384], output y bf16 [BT][128].
// ---------------------------------------------------------------------------
__global__ __launch_bounds__(256) void attn_mfma(
    const unsigned short* __restrict__ qkv, unsigned short* __restrict__ y)
{
  __shared__ short Ks[128 * 32];
  __shared__ short Vt[32 * 128];
  __shared__ short Ps[4][32 * 128];
  const int tid = threadIdx.x;
  const int b = blockIdx.x >> 2, h = blockIdx.x & 3;
  const unsigned short* __restrict__ base = qkv + (size_t)b * 128 * 384 + h * 32;
#pragma unroll
  for (int p = 0; p < 2; ++p) {
    const int idx = tid + p * 256;
    const int s = idx >> 2, c8 = idx & 3;
    const bf16x8 v = *reinterpret_cast<const bf16x8*>(base + (size_t)s * 384 + 128 + c8 * 8);
    const int chunk = c8 ^ ((s >> 1) & 3);
    *reinterpret_cast<bf16x8*>(&Ks[s * 32 + chunk * 8]) = v;
  }
#pragma unroll
  for (int p = 0; p < 4; ++p) {
    const int idx = tid + p * 256;
    const int s = idx >> 3, c4 = idx & 7;
    const ushort4 v = *reinterpret_cast<const ushort4*>(base + (size_t)s * 384 + 256 + c4 * 4);
    const int schunk = s >> 3, soff = s & 7;
#pragma unroll
    for (int k = 0; k < 4; ++k) {
      const int d = c4 * 4 + k;
      const unsigned short vv = (k == 0) ? v.x : (k == 1) ? v.y : (k == 2) ? v.z : v.w;
      Vt[d * 128 + ((schunk ^ (d & 7)) << 3) + soff] = (short)vv;
    }
  }
  const int w = tid >> 6, l = tid & 63;
  const int g = l >> 4, lr = l & 15;
  bf16x8 qa[2];
#pragma unroll
  for (int mi = 0; mi < 2; ++mi) {
    const int row = w * 32 + mi * 16 + lr;
    qa[mi] = *reinterpret_cast<const bf16x8*>(base + (size_t)row * 384 + g * 8);
  }
  __syncthreads();
  const int ntmax = 2 * w + 1;
  bf16x8 ka[8];
#pragma unroll
  for (int nt = 0; nt < 8; ++nt)
    if (nt <= ntmax) {
      const int s = nt * 16 + lr;
      const int chunk = g ^ ((s >> 1) & 3);
      ka[nt] = *reinterpret_cast<const bf16x8*>(&Ks[s * 32 + chunk * 8]);
    }
  f32x4 sacc[2][8];
#pragma unroll
  for (int mi = 0; mi < 2; ++mi)
#pragma unroll
    for (int nt = 0; nt < 8; ++nt) sacc[mi][nt] = {0.f, 0.f, 0.f, 0.f};
#pragma unroll
  for (int mi = 0; mi < 2; ++mi)
#pragma unroll
    for (int nt = 0; nt < 8; ++nt)
      if (nt <= ntmax)
        sacc[mi][nt] = __builtin_amdgcn_mfma_f32_16x16x32_bf16(qa[mi], ka[nt], sacc[mi][nt], 0, 0, 0);
  const float scl = 0.17677669529663687f; // 1/sqrt(32)
  float rv[2][4];
  short* const pw = Ps[w];
#pragma unroll
  for (int mi = 0; mi < 2; ++mi) {
#pragma unroll
    for (int j = 0; j < 4; ++j) {
      const int row = w * 32 + mi * 16 + g * 4 + j;
      float mx = -3.4e38f;
#pragma unroll
      for (int nt = 0; nt < 8; ++nt)
        if (nt <= ntmax) {
          const int col = nt * 16 + lr;
          const float val = sacc[mi][nt][j] * scl;
          if (col <= row) mx = fmaxf(mx, val);
        }
      mx = redmax16(mx);
      float sum = 0.f;
      const int rl = mi * 16 + g * 4 + j;
#pragma unroll
      for (int nt = 0; nt < 8; ++nt)
        if (nt <= ntmax) {
          const int col = nt * 16 + lr;
          const float val = sacc[mi][nt][j] * scl;
          const float pv = (col <= row) ? __expf(val - mx) : 0.f;
          sum += pv;
          const int chunk = (2 * nt + (lr >> 3)) ^ (rl & 7);
          pw[rl * 128 + chunk * 8 + (lr & 7)] = bf16c(pv);
        }
      sum = red16(sum);
      rv[mi][j] = 1.f / sum;
    }
  }
  f32x4 oacc[2][2];
#pragma unroll
  for (int mi = 0; mi < 2; ++mi)
#pragma unroll
    for (int nt = 0; nt < 2; ++nt) oacc[mi][nt] = {0.f, 0.f, 0.f, 0.f};
#pragma unroll
  for (int kt = 0; kt < 4; ++kt)
    if (kt <= w) {
      bf16x8 pa[2], va[2];
#pragma unroll
      for (int mi = 0; mi < 2; ++mi) {
        const int rl = mi * 16 + lr;
        const int chunk = (4 * kt + g) ^ (rl & 7);
        pa[mi] = *reinterpret_cast<const bf16x8*>(&pw[rl * 128 + chunk * 8]);
      }
#pragma unroll
      for (int nt = 0; nt < 2; ++nt) {
        const int d = nt * 16 + lr;
        const int chunk = (4 * kt + g) ^ (d & 7);
        va[nt] = *reinterpret_cast<const bf16x8*>(&Vt[d * 128 + chunk * 8]);
      }
#pragma unroll
      for (int mi = 0; mi < 2; ++mi)
#pragma unroll
        for (int nt = 0; nt < 2; ++nt)
          oacc[mi][nt] = __builtin_amdgcn_mfma_f32_16x16x32_bf16(pa[mi], va[nt], oacc[mi][nt], 0, 0, 0);
    }
#pragma unroll
  for (int mi = 0; mi < 2; ++mi)
#pragma unroll
    for (int nt = 0; nt < 2; ++nt)
#pragma unroll
      for (int j = 0; j < 4; ++j) {
        const int row = w * 32 + mi * 16 + g * 4 + j;
        y[((size_t)b * 128 + row) * 128 + h * 32 + nt * 16 + lr] =
            (unsigned short)bf16c(oacc[mi][nt][j] * rv[mi][j]);
      }
}

// ---------------------------------------------------------------------------
extern "C" void kernel_launch(void* const* d_in, const int* in_sizes, int n_in,
                              void* d_out, int out_size, void* d_ws, size_t ws_size,
                              hipStream_t stream)
{
  const float* x        = (const float*)d_in[0];
  const int*   ids      = (const int*)d_in[1];
  const int*   mults    = (const int*)d_in[2];
  const float* table    = (const float*)d_in[3];
  const float* val_w    = (const float*)d_in[4];
  const float* val_b    = (const float*)d_in[5];
  const float* key_w    = (const float*)d_in[6];
  const float* key_b    = (const float*)d_in[7];
  const float* nq_w     = (const float*)d_in[8];
  const float* nk_w     = (const float*)d_in[9];
  const float* conv_w   = (const float*)d_in[10];
  const float* cnw      = (const float*)d_in[11];
  const float* a_coef   = (const float*)d_in[12];
  const float* a_pre_w  = (const float*)d_in[13];
  const float* a_pre_b  = (const float*)d_in[14];
  const float* a_post_w = (const float*)d_in[15];
  const float* a_post_b = (const float*)d_in[16];
  const float* a_res_w  = (const float*)d_in[17];
  const float* a_res_b  = (const float*)d_in[18];
  const float* a_apre   = (const float*)d_in[19];
  const float* a_apost  = (const float*)d_in[20];
  const float* a_ares   = (const float*)d_in[21];
  const float* a_ln_w   = (const float*)d_in[22];
  const float* qkv_w    = (const float*)d_in[23];
  const float* qkv_b    = (const float*)d_in[24];
  const float* proj_w   = (const float*)d_in[25];
  const float* proj_b   = (const float*)d_in[26];
  const float* m_coef   = (const float*)d_in[27];
  const float* m_pre_w  = (const float*)d_in[28];
  const float* m_pre_b  = (const float*)d_in[29];
  const float* m_post_w = (const float*)d_in[30];
  const float* m_post_b = (const float*)d_in[31];
  const float* m_res_w  = (const float*)d_in[32];
  const float* m_res_b  = (const float*)d_in[33];
  const float* m_apre   = (const float*)d_in[34];
  const float* m_apost  = (const float*)d_in[35];
  const float* m_ares   = (const float*)d_in[36];
  const float* m_ln_w   = (const float*)d_in[37];
  const float* mlp_w1   = (const float*)d_in[38];
  const float* mlp_b1   = (const float*)d_in[39];
  const float* mlp_w2   = (const float*)d_in[40];
  const float* mlp_b2   = (const float*)d_in[41];

  float* out = (float*)d_out;
  float* ws  = (float*)d_ws;
  float* vbase  = ws;                         // BT*128 slot (bf16 used)
  float* proj24 = vbase + (size_t)BT * 128;   // BT*32
  float* hresb  = proj24 + (size_t)BT * 32;   // BT*16
  float* hpsb   = hresb + (size_t)BT * 16;    // BT
  float* inv1   = hpsb + (size_t)BT;          // BT
  float* inv2   = inv1 + (size_t)BT;          // BT
  float* bpk_a  = inv2 + (size_t)BT;          // 32
  float* bpk_m  = bpk_a + 32;                 // 32
  short* wt_qkv  = (short*)(bpk_m + 32);      // 384*128
  short* wt_proj = wt_qkv  + 49152;           // 128*128
  short* wt_mlp1 = wt_proj + 16384;           // 512*128
  short* wt_mlp2 = wt_mlp1 + 65536;           // 128*512
  short* wt_eng  = wt_mlp2 + 65536;           // 640*256
  short* wpk_a   = wt_eng  + 163840;          // 32*512
  short* wpk_m   = wpk_a   + 16384;           // 32*512
  unsigned short* xab = (unsigned short*)(wpk_m + 16384); // BT*128 bf16 (attn-out alias)
  unsigned short* big = xab + (size_t)BT * 128;           // BT*512 bf16: kraw -> qkv -> h
  unsigned short* x1b = big + (size_t)BT * 512;           // BT*512 bf16 state x1
  unsigned short* x2b = x1b + (size_t)BT * 512;           // BT*512 bf16 state x2
  unsigned short* tableb = x2b + (size_t)BT * 512;        // 16384*64 bf16
  unsigned short* vbaseb = (unsigned short*)vbase;        // BT*128 bf16
  unsigned short* y1b = xab;                              // alias: attn out

  prep<<<5633, 256, 0, stream>>>(qkv_w, proj_w, mlp_w1, mlp_w2, val_w, key_w, table,
                                 a_res_w, a_pre_w, a_post_w, m_res_w, m_pre_w, m_post_w,
                                 a_res_b, a_pre_b, a_post_b, m_res_b, m_pre_b, m_post_b,
                                 wt_qkv, wt_proj, wt_mlp1, wt_mlp2, wt_eng,
                                 wpk_a, wpk_m, bpk_a, bpk_m, tableb);

  // ---- engram ----
  eng_mgemm<<<dim3(BT / 128, 5), 256, 0, stream>>>(ids, mults, tableb, val_b, wt_eng,
                                                   vbaseb, big);
  fused_gateconv<<<BT / 16, 512, 0, stream>>>(big, x, vbaseb, key_b, nk_w, nq_w,
                                              conv_w, cnw, x1b, inv1);

  // ---- mhc (attention) ----
  mgemm32<<<BT / 64, 256, 0, stream>>>(x1b, 512, wpk_a, bpk_a, proj24, 512, inv1, a_coef);
  mhc_sink2<<<BT / 4, 256, 0, stream>>>(proj24, x1b, a_apre, a_apost, a_ares, a_ln_w,
                                        xab, hresb, hpsb);
  mgemm_bf16A<3, 0><<<dim3(BT / 128, 3), 256, 0, stream>>>(xab, wt_qkv, qkv_b, big);
  attn_mfma<<<1024, 256, 0, stream>>>(big, y1b);
  gemm_combine<2, true, true><<<BT / 64, 512, 0, stream>>>(
      y1b, 128, wt_proj, proj_b, x1b, hresb, hpsb, (void*)x2b, inv2);

  // ---- mhc (mlp) ----
  mgemm32<<<BT / 64, 256, 0, stream>>>(x2b, 512, wpk_m, bpk_m, proj24, 512, inv2, m_coef);
  mhc_sink2<<<BT / 4, 256, 0, stream>>>(proj24, x2b, m_apre, m_apost, m_ares, m_ln_w,
                                        xab, hresb, hpsb);
  mgemm_bf16A<4, 1><<<dim3(BT / 128, 4), 256, 0, stream>>>(xab, wt_mlp1, mlp_b1, big);
  gemm_combine<8, false, false><<<BT / 64, 512, 0, stream>>>(
      big, 512, wt_mlp2, mlp_b2, x2b, hresb, hpsb, (void*)out, nullptr);

  (void)in_sizes; (void)n_in; (void)out_size; (void)ws_size;
}